// Round 10
// baseline (391.927 us; speedup 1.0000x reference)
//
#include <hip/hip_runtime.h>

typedef unsigned short u16;
typedef unsigned int   u32;

__device__ __forceinline__ float bf2f(u16 h){ return __uint_as_float(((u32)h)<<16); }
// weight load: bf16 or fp32 selected by runtime flag (wave-uniform branch)
__device__ __forceinline__ float ldw(const void* p, size_t i, int bf){
  return bf ? bf2f(((const u16*)p)[i]) : ((const float*)p)[i];
}

// ---------------- constants ----------------
#define BTASK   2048
#define KTOT    10320      // 6*1720
#define NP      40
#define KS      30         // k-split segments of the main pass
#define SEGLEN  344        // 30*344 = 10320; chunks 5x64 + 24

// ws byte offsets (256-aligned). Peak usage ~11.3 MiB (proven safe).
#define OFF_TBL  0u          // 288 (70-float pix table)
#define OFF_WF   36096u      // 1,651,200 (10320 rows x 40 f32)
#define OFF_HR   1694976u    // 288,000
#define OFF_WO   1982976u    // 17,200
#define OFF_RR   2000384u    // 8,000
#define OFF_BF   2008576u    // 160
#define OFF_FLG  2008832u    // 4
#define OFF_O12  2009088u    // 17,200
#define OFF_BCH  2026368u    // 6,400 bias-chain buffers
// transient ping-pong regions (3,840,000 B each; all dead before main pass)
#define OFF_P    2032896u    // S3 parts -> Hfp parts -> R2 parts
#define OFF_Q    5872896u    // S2 parts -> R3 parts -> R1 parts
#define OFF_PART 2032896u    // 9,830,400 (aliases P+Q; ends 11,863,296)

// bias-chain float indices within OFF_BCH
#define B_BO1  0
#define B_BI1  64
#define B_BN1  384
#define B_BOBJ 896
#define B_BIO  960
#define B_BN2  1280
#define B_BH   1536

// ---------------- pix table (+dtype detect merged): pix[c,i,j] = tbl[c]+tbl[10+i]+tbl[40+j]
__global__ void table_kernel(const u32* __restrict__ mask0,
                             const void* wc, const void* bc, const void* wx, const void* bx,
                             const void* wy, const void* by, const void* wcb, const void* bcb,
                             int* __restrict__ flag, float* __restrict__ tbl){
  int bf = (mask0[0] == 0x3F803F80u) ? 1 : 0;
  int e = threadIdx.x;
  if (e == 0) flag[0] = bf;
  if (e < 10)      tbl[e] = ldw(wcb,0,bf)*(ldw(wc,e,bf)+ldw(bc,0,bf)) + ldw(bcb,0,bf);
  else if (e < 40) tbl[e] = ldw(wcb,1,bf)*(ldw(wx,e-10,bf)+ldw(bx,0,bf));
  else if (e < 70) tbl[e] = ldw(wcb,2,bf)*(ldw(wy,e-40,bf)+ldw(by,0,bf));
}

// ---------------- 32x32-tile GEMM, fp32 accum, split-K via gridDim.z, B part-sum folded
template<int AW, int BW>
__launch_bounds__(256)
__global__ void gemm32(const void* __restrict__ A, const void* __restrict__ Bv,
                       float* __restrict__ Cp, int M, int N, int K, int nB, int bStride,
                       const int* __restrict__ flag){
  __shared__ float As[16][33];
  __shared__ float Bs[16][33];
  int bf = flag[0];
  const float* Af = (const float*)A;
  const float* Bf = (const float*)Bv;
  int tid = threadIdx.x;
  int m0 = blockIdx.x*32, n0 = blockIdx.y*32;
  int Z = gridDim.z;
  int kc = (K + Z - 1)/Z;
  int k0 = blockIdx.z*kc, k1 = min(K, k0 + kc);
  float acc[2][2] = {};
  int tm = tid & 15, tn = tid >> 4;
  for (int kb = k0; kb < k1; kb += 16) {
    #pragma unroll
    for (int it = 0; it < 2; it++) {
      int idx = tid + it*256;
      { int kk = idx & 15, m = idx >> 4;
        float v = 0.f; int gm = m0+m, gk = kb+kk;
        if (gm < M && gk < k1)
          v = AW ? ldw(A, (size_t)gm*K + gk, bf) : Af[(size_t)gm*K + gk];
        As[kk][m] = v; }
      { int n = idx & 31, kk = idx >> 5;
        float v = 0.f; int gn = n0+n, gk = kb+kk;
        if (gn < N && gk < k1) {
          size_t off = (size_t)gk*N + gn;
          if (BW) v = ldw(Bv, off, bf);
          else for (int s = 0; s < nB; s++) v += Bf[(size_t)s*bStride + off];
        }
        Bs[kk][n] = v; }
    }
    __syncthreads();
    #pragma unroll
    for (int kk = 0; kk < 16; kk++) {
      float a0 = As[kk][tm*2], a1 = As[kk][tm*2+1];
      float b0 = Bs[kk][tn*2], b1 = Bs[kk][tn*2+1];
      acc[0][0] += a0*b0; acc[0][1] += a0*b1;
      acc[1][0] += a1*b0; acc[1][1] += a1*b1;
    }
    __syncthreads();
  }
  float* C = Cp + (size_t)blockIdx.z*M*N;
  #pragma unroll
  for (int i = 0; i < 2; i++)
    #pragma unroll
    for (int j = 0; j < 2; j++) {
      int gm = m0 + tm*2 + i, gn = n0 + tn*2 + j;
      if (gm < M && gn < N) C[(size_t)gm*N + gn] = acc[i][j];
    }
}

// ---------------- Hresh[j*240 + p*40 + n] = sum_{s<8} Hfp[s][(p*300+j)*40 + n]
__global__ void repack_kernel(const float* __restrict__ Hfp, float* __restrict__ Hresh){
  int oi = blockIdx.x*256 + threadIdx.x;
  if (oi >= 72000) return;
  int j = oi/240, c = oi%240, p = c/40, n = c%40;
  float s = 0.f;
  #pragma unroll
  for (int sp = 0; sp < 8; sp++) s += Hfp[(size_t)sp*72000 + (p*300+j)*40 + n];
  Hresh[oi] = s;
}

// ---------------- Wfull[k*40+n], k = p*1720+g*86+t: sum_d wobj[t,d]*R1[(g*50+d)][p*40+n]
__global__ void wfull_kernel(const float* __restrict__ wobj, const float* __restrict__ R1p,
                             float* __restrict__ Wfull){
  int oi = blockIdx.x*256 + threadIdx.x;
  if (oi >= KTOT*NP) return;
  int k = oi/NP, n = oi%NP;
  int p = k/1720, r = k%1720, g = r/86, t = r%86;
  float s = 0.f;
  #pragma unroll 2
  for (int d = 0; d < 50; d++) {
    size_t off = (size_t)(g*50+d)*240 + p*40 + n;
    float rv = R1p[off] + R1p[240000+off] + R1p[480000+off] + R1p[720000+off];
    s += wobj[t*50 + d] * rv;
  }
  Wfull[oi] = s;
}

// ---------------- r1red[j*40+n] = sum over 480 terms (4 parts x 20 g x 6 p), 8-way reduce
__global__ void r1red_kernel(const float* __restrict__ R1p, float* __restrict__ r1red){
  __shared__ float red[8][33];
  int nt = threadIdx.x & 31, rt = threadIdx.x >> 5;
  int oi = blockIdx.x*32 + nt;
  int j = (oi < 2000) ? oi/40 : 0, n = (oi < 2000) ? oi%40 : 0;
  float s = 0.f;
  if (oi < 2000) {
    #pragma unroll 2
    for (int u = rt; u < 480; u += 8) {
      int sp = u/120, rm = u - sp*120, g = rm/6, p = rm - g*6;
      s += R1p[(size_t)sp*240000 + (g*50+j)*240 + p*40 + n];
    }
  }
  red[rt][nt] = s;
  __syncthreads();
  if (rt < 4) red[rt][nt] += red[rt+4][nt];
  __syncthreads();
  if (rt < 2) red[rt][nt] += red[rt+2][nt];
  __syncthreads();
  if (rt == 0 && oi < 2000) r1red[oi] = red[0][nt] + red[1][nt];
}

// ---------------- merged 3-job GEMV: out[n] = b2[n] + sum_k x[k]*W[k*N+n]
__global__ void gemv3_kernel(
    const void* x0, const void* W0, const void* b0, float* o0, int N0, int K0, int xw0,
    const void* x1, const void* W1, const void* b1, float* o1, int N1, int K1, int xw1,
    const void* x2, const void* W2, const void* b2, float* o2, int N2, int K2, int xw2,
    int s1, int s2, const int* __restrict__ flag){
  __shared__ float red[16][17];
  int bf = flag[0];
  int b = blockIdx.x;
  const void *x, *W, *bb; float* o; int N, K, xw, lb;
  if (b < s1)      { x=x0; W=W0; bb=b0; o=o0; N=N0; K=K0; xw=xw0; lb=b; }
  else if (b < s2) { x=x1; W=W1; bb=b1; o=o1; N=N1; K=K1; xw=xw1; lb=b-s1; }
  else             { x=x2; W=W2; bb=b2; o=o2; N=N2; K=K2; xw=xw2; lb=b-s2; }
  int nt = threadIdx.x & 15, kt = threadIdx.x >> 4;
  int n = lb*16 + nt;
  float s = 0.f;
  if (n < N) {
    #pragma unroll 4
    for (int k = kt; k < K; k += 16) {
      float xv = xw ? ldw(x,k,bf) : ((const float*)x)[k];
      s += xv * ldw(W,(size_t)k*N+n,bf);
    }
  }
  red[kt][nt] = s;
  __syncthreads();
  for (int st = 8; st > 0; st >>= 1) {
    if (kt < st) red[kt][nt] += red[kt+st][nt];
    __syncthreads();
  }
  if (kt == 0 && n < N) o[n] = red[0][nt] + ldw(bb,n,bf);
}

// ---------------- final bias combine
__global__ void biasfin_kernel(const float* __restrict__ bch,
                               const float* __restrict__ Hresh,
                               const float* __restrict__ r1red,
                               float* __restrict__ biasf){
  __shared__ float red[4][64];
  int nt = threadIdx.x & 63;
  int kt = threadIdx.x >> 6;
  int n = nt;
  float s = 0.f;
  if (n < NP) {
    for (int j = kt; j < 300; j += 4) {
      float h = 0.f;
      #pragma unroll
      for (int p = 0; p < 6; p++) h += Hresh[j*240 + p*40 + n];
      s += bch[B_BIO + j] * h;
    }
    for (int j = kt; j < 50; j += 4)
      s += bch[B_BOBJ + j] * r1red[j*40 + n];
  }
  red[kt][nt] = s;
  __syncthreads();
  if (kt == 0 && n < NP)
    biasf[n] = red[0][nt]+red[1][nt]+red[2][nt]+red[3][nt] + bch[B_BH + n];
}

// ---------------- issue: load one quad's raw data into registers (no LDS, no waits)
__device__ __forceinline__ void gissue(int t, int q, int kc0, int task0,
    const int* __restrict__ c_idx, const int* __restrict__ i_idx,
    const int* __restrict__ j_idx, const void* __restrict__ maskv, int bf,
    int4& c4, int4& i4, int4& j4, int4& m4){
  int gk = kc0 + (q << 2);
  size_t gb = (size_t)(task0 + t)*KTOT + gk;
  c4 = *(const int4*)(c_idx + gb);
  i4 = *(const int4*)(i_idx + gb);
  j4 = *(const int4*)(j_idx + gb);
  if (bf) { int2 mm = *(const int2*)((const u16*)maskv + gb); m4.x = mm.x; m4.y = mm.y; }
  else    { m4 = *(const int4*)((const char*)maskv + gb*4); }
}

// ---------------- materialize: tbl+mask math, write vbuf
__device__ __forceinline__ void gwrite(int t, int q, int bf,
    const float* __restrict__ tbl, float* __restrict__ vbuf,
    const int4& c4, const int4& i4, const int4& j4, const int4& m4){
  float mv[4];
  if (bf) {
    u32 a = (u32)m4.x, b = (u32)m4.y;
    mv[0]=bf2f((u16)(a&0xFFFFu)); mv[1]=bf2f((u16)(a>>16));
    mv[2]=bf2f((u16)(b&0xFFFFu)); mv[3]=bf2f((u16)(b>>16));
  } else {
    mv[0]=__int_as_float(m4.x); mv[1]=__int_as_float(m4.y);
    mv[2]=__int_as_float(m4.z); mv[3]=__int_as_float(m4.w);
  }
  int cc[4]={c4.x,c4.y,c4.z,c4.w}, ii[4]={i4.x,i4.y,i4.z,i4.w}, jj[4]={j4.x,j4.y,j4.z,j4.w};
  int kk = q << 2;
  #pragma unroll
  for (int x = 0; x < 4; x++)
    vbuf[(kk+x)*65 + t] = (tbl[cc[x]] + tbl[10+ii[x]] + tbl[40+jj[x]]) * mv[x];
}

// ---------------- main: reg-staged pipeline: issue(c+1) || compute(c); W tile in LDS
__launch_bounds__(512, 4)
__global__ void main_gather(const int* __restrict__ c_idx, const int* __restrict__ i_idx,
                            const int* __restrict__ j_idx, const void* __restrict__ maskv,
                            const float* __restrict__ tblg, const float* __restrict__ Wfull,
                            const int* __restrict__ flag, float* __restrict__ part){
  __shared__ float tbl[72];
  __shared__ float vbuf[64*65];    // [k][task], 65 stride (conflict-free compute reads)
  __shared__ float wlds[2560];     // W chunk [64 k][40 n]
  int bf = flag[0];
  int tid = threadIdx.x;
  if (tid < 70) tbl[tid] = tblg[tid];
  int task0 = blockIdx.x << 6;            // 32 blocks x 64 tasks
  int kseg0 = blockIdx.y * SEGLEN;        // 30 segments x 344
  int lane = tid & 63;                    // task within block
  int ngbase = __builtin_amdgcn_readfirstlane(tid >> 6) * 5;  // wave -> 5 cols
  float acc[5] = {};
  int4 qc[2], qi[2], qj[2], qm[2];
  float wreg[5];

  auto issue_chunk = [&](int cb){
    int kc0 = kseg0 + cb*64;
    if (cb < 5) {
      gissue(tid>>4, tid&15, kc0, task0, c_idx, i_idx, j_idx, maskv, bf,
             qc[0], qi[0], qj[0], qm[0]);
      int e4 = tid + 512;
      gissue(e4>>4, e4&15, kc0, task0, c_idx, i_idx, j_idx, maskv, bf,
             qc[1], qi[1], qj[1], qm[1]);
      #pragma unroll
      for (int j2 = 0; j2 < 5; j2++) wreg[j2] = Wfull[(size_t)kc0*NP + tid + j2*512];
    } else {                               // tail: kc=24 -> 384 quads, 960 W floats
      if (tid < 384) {
        int t = (int)((u32)tid / 6u);
        gissue(t, tid - t*6, kc0, task0, c_idx, i_idx, j_idx, maskv, bf,
               qc[0], qi[0], qj[0], qm[0]);
      }
      #pragma unroll
      for (int j2 = 0; j2 < 2; j2++) {
        int e = tid + j2*512;
        if (e < 960) wreg[j2] = Wfull[(size_t)kc0*NP + e];
      }
    }
  };
  auto write_chunk = [&](int cb){
    if (cb < 5) {
      gwrite(tid>>4, tid&15, bf, tbl, vbuf, qc[0], qi[0], qj[0], qm[0]);
      int e4 = tid + 512;
      gwrite(e4>>4, e4&15, bf, tbl, vbuf, qc[1], qi[1], qj[1], qm[1]);
      #pragma unroll
      for (int j2 = 0; j2 < 5; j2++) wlds[tid + j2*512] = wreg[j2];
    } else {
      if (tid < 384) {
        int t = (int)((u32)tid / 6u);
        gwrite(t, tid - t*6, bf, tbl, vbuf, qc[0], qi[0], qj[0], qm[0]);
      }
      #pragma unroll
      for (int j2 = 0; j2 < 2; j2++) {
        int e = tid + j2*512;
        if (e < 960) wlds[e] = wreg[j2];
      }
    }
  };

  // prologue: stage chunk 0
  issue_chunk(0);
  write_chunk(0);
  __syncthreads();
  for (int cb = 0; cb < 6; cb++) {
    int kc = (cb == 5) ? 24 : 64;
    if (cb < 5) issue_chunk(cb+1);      // loads fly during compute
    for (int k = 0; k < kc; k++) {
      float v = vbuf[k*65 + lane];
      const float* wr = &wlds[k*40 + ngbase];   // wave-uniform -> LDS broadcast
      #pragma unroll
      for (int n = 0; n < 5; n++) acc[n] += v * wr[n];
    }
    __syncthreads();                    // all waves done reading LDS
    if (cb < 5) write_chunk(cb+1);      // waitcnt lands here, under-lapped by compute
    __syncthreads();                    // LDS ready for next compute
  }
  size_t base = ((size_t)blockIdx.y*NP + ngbase)*BTASK + task0 + lane;
  #pragma unroll
  for (int n = 0; n < 5; n++) part[base + (size_t)n*BTASK] = acc[n];
}

// ---------------- reduce partials + bias, emit FP32; coalesced part reads
__global__ void main_reduce(const float* __restrict__ part, const float* __restrict__ biasf,
                            float* __restrict__ out){
  int id = blockIdx.x*256 + threadIdx.x;      // id = col*2048 + task
  if (id >= BTASK*NP) return;
  int col = id >> 11, t = id & 2047;
  float s = biasf[col];
  #pragma unroll
  for (int z = 0; z < KS; z++) s += part[((size_t)z*NP + col)*BTASK + t];
  out[t*NP + col] = s;
}

extern "C" void kernel_launch(void* const* d_in, const int* in_sizes, int n_in,
                              void* d_out, int out_size, void* d_ws, size_t ws_size,
                              hipStream_t stream){
  const int* c_idx = (const int*)d_in[0];
  const int* i_idx = (const int*)d_in[1];
  const int* j_idx = (const int*)d_in[2];
  const void* mask = d_in[3];
  const void *w_color=d_in[4], *b_color=d_in[5], *w_x=d_in[6], *b_x=d_in[7];
  const void *w_y=d_in[8], *b_y=d_in[9], *w_comb=d_in[10], *b_comb=d_in[11];
  const void *oW1=d_in[12], *ob1=d_in[13], *oW2=d_in[14], *ob2=d_in[15];
  const void *oW3=d_in[16], *ob3=d_in[17];
  const void *ioW1=d_in[18], *iob1=d_in[19], *ioW2=d_in[20], *iob2=d_in[21];
  const void *ioW3=d_in[22], *iob3=d_in[23];
  const void *nW1=d_in[24], *nb1=d_in[25], *nW2=d_in[26], *nb2=d_in[27];
  const void *nW3=d_in[28], *nb3=d_in[29], *nW4=d_in[30], *nb4=d_in[31];

  char* ws = (char*)d_ws;
  float* tblw  = (float*)(ws + OFF_TBL);
  float* Wfull = (float*)(ws + OFF_WF);
  float* Hresh = (float*)(ws + OFF_HR);
  float* wobj  = (float*)(ws + OFF_WO);
  float* r1red = (float*)(ws + OFF_RR);
  float* biasf = (float*)(ws + OFF_BF);
  int*   flag  = (int*)  (ws + OFF_FLG);
  float* o12   = (float*)(ws + OFF_O12);
  float* bch   = (float*)(ws + OFF_BCH);
  float* P     = (float*)(ws + OFF_P);
  float* Q     = (float*)(ws + OFF_Q);
  float* part  = (float*)(ws + OFF_PART);

  table_kernel<<<1, 128, 0, stream>>>((const u32*)mask, w_color, b_color, w_x, b_x,
                                      w_y, b_y, w_comb, b_comb, flag, tblw);
  // obj chain: o12 = oW1@oW2, Wobj = o12@oW3
  gemm32<1,1><<<dim3(3,2,1),  256, 0, stream>>>(oW1, oW2, o12, 86, 50, 86, 1, 0, flag);
  gemm32<0,1><<<dim3(3,2,1),  256, 0, stream>>>(o12, oW3, wobj, 86, 50, 50, 1, 0, flag);
  // head chain (right-assoc, split-K parts): S3 -> P, S2 -> Q, Hfp -> P
  gemm32<1,1><<<dim3(16,2,8), 256, 0, stream>>>(nW3, nW4, P, 512, 40, 256, 1, 0, flag);
  gemm32<1,0><<<dim3(32,2,8), 256, 0, stream>>>(nW2, P, Q, 1024, 40, 512, 8, 512*40, flag);
  gemm32<1,0><<<dim3(57,2,8), 256, 0, stream>>>(nW1, Q, P, 1800, 40, 1024, 8, 1024*40, flag);
  repack_kernel<<<282, 256, 0, stream>>>(P, Hresh);
  // io chain: R3 -> Q, R2 -> P, R1 -> Q
  gemm32<1,0><<<dim3(10,8,8), 256, 0, stream>>>(ioW3, Hresh, Q, 300, 240, 300, 1, 0, flag);
  gemm32<1,0><<<dim3(32,8,4), 256, 0, stream>>>(ioW2, Q, P, 1000, 240, 300, 8, 72000, flag);
  gemm32<1,0><<<dim3(32,8,4), 256, 0, stream>>>(ioW1, P, Q, 1000, 240, 1000, 4, 240000, flag);
  // composed weight (folds R1 parts in Q)
  wfull_kernel<<<1613, 256, 0, stream>>>(wobj, Q, Wfull);
  r1red_kernel<<<63, 256, 0, stream>>>(Q, r1red);
  // bias chain: 3 merged levels
  gemv3_kernel<<<55, 256, 0, stream>>>(
      ob1,  oW2,  ob2,  bch+B_BO1,  50,   86, 1,
      iob1, ioW2, iob2, bch+B_BI1, 300, 1000, 1,
      nb1,  nW2,  nb2,  bch+B_BN1, 512, 1024, 1,
      4, 23, flag);
  gemv3_kernel<<<39, 256, 0, stream>>>(
      bch+B_BO1, oW3,  ob3,  bch+B_BOBJ,  50,  50, 0,
      bch+B_BI1, ioW3, iob3, bch+B_BIO,  300, 300, 0,
      bch+B_BN1, nW3,  nb3,  bch+B_BN2,  256, 512, 0,
      4, 23, flag);
  gemv3_kernel<<<3, 256, 0, stream>>>(
      bch+B_BN2, nW4, nb4, bch+B_BH, 40, 256, 0,
      bch+B_BN2, nW4, nb4, bch+B_BH, 40, 256, 0,
      bch+B_BN2, nW4, nb4, bch+B_BH, 40, 256, 0,
      3, 3, flag);
  biasfin_kernel<<<1, 256, 0, stream>>>(bch, Hresh, r1red, biasf);
  // main pass
  main_gather<<<dim3(32, KS), 512, 0, stream>>>(c_idx, i_idx, j_idx, mask, tblw, Wfull,
                                                flag, part);
  main_reduce<<<320, 256, 0, stream>>>(part, biasf, (float*)d_out);
}